// Round 18
// baseline (237.805 us; speedup 1.0000x reference)
//
#include <hip/hip_runtime.h>
#include <cstdint>

#define BB 2
#define SS 2048
#define DD 1024
#define HH 16
#define HDIM 64
#define MM (BB*SS)      // 4096
#define N3 (3*DD)       // 3072

typedef __attribute__((ext_vector_type(4))) float f32x4;
typedef __attribute__((ext_vector_type(16))) float f32x16;
typedef __attribute__((ext_vector_type(8))) __bf16 bf16x8;

static __device__ __forceinline__ unsigned short f2bf_fast(float f) {
  __bf16 h = (__bf16)f;
  return __builtin_bit_cast(unsigned short, h);
}

static __device__ __forceinline__ uint4 pack8f(const float4 a, const float4 b) {
  union { unsigned short us[8]; uint4 v; } pk;
  pk.us[0] = f2bf_fast(a.x); pk.us[1] = f2bf_fast(a.y); pk.us[2] = f2bf_fast(a.z); pk.us[3] = f2bf_fast(a.w);
  pk.us[4] = f2bf_fast(b.x); pk.us[5] = f2bf_fast(b.y); pk.us[6] = f2bf_fast(b.z); pk.us[7] = f2bf_fast(b.w);
  return pk.v;
}

static __device__ __forceinline__ void gload16(const unsigned short* g, unsigned short* l) {
  __builtin_amdgcn_global_load_lds(
      (const __attribute__((address_space(1))) void*)g,
      (__attribute__((address_space(3))) void*)l, 16, 0, 0);
}

// ---------------------------------------------------------------------------
// One-time fp32 -> bf16 conversion of x, W_w, proj_w
// ---------------------------------------------------------------------------
__global__ __launch_bounds__(256) void cvt_kernel(
    const float* __restrict__ x, const float* __restrict__ Ww,
    const float* __restrict__ pw,
    unsigned short* __restrict__ xb, unsigned short* __restrict__ Wwb,
    unsigned short* __restrict__ pwb) {
  const size_t i = ((size_t)blockIdx.x * 256 + threadIdx.x) * 8;
  const float* src;
  unsigned short* dst;
  if (i < 4194304u)       { src = x  + i;            dst = xb  + i; }
  else if (i < 7340032u)  { src = Ww + (i - 4194304u); dst = Wwb + (i - 4194304u); }
  else                    { src = pw + (i - 7340032u); dst = pwb + (i - 7340032u); }
  const float4* s4 = (const float4*)src;
  *(uint4*)dst = pack8f(s4[0], s4[1]);
}

// ---------------------------------------------------------------------------
// QKV GEMM (bf16 in), BK=64 via two 128x32 half-buffers per operand.
// ALL outputs (q, k, v) go through an LDS transpose tile -> coalesced
// uint4 stores. q pre-scaled by log2e/32; v transposed to [b,h,hd,s].
// (r17 exact)
// ---------------------------------------------------------------------------
__global__ __launch_bounds__(256) void gemm_qkv(
    const unsigned short* __restrict__ xb, const unsigned short* __restrict__ Wwb,
    const float* __restrict__ Wb,
    unsigned short* __restrict__ qb, unsigned short* __restrict__ kb,
    unsigned short* __restrict__ vbT) {
  __shared__ __align__(16) unsigned short Sh[128 * 136];   // 34.8 KB
  unsigned short* As0 = Sh;                 // 128x32 (k lo)
  unsigned short* As1 = Sh + 4096;          // 128x32 (k hi)
  unsigned short* Bs0 = Sh + 8192;
  unsigned short* Bs1 = Sh + 12288;
  const int t = threadIdx.x;
  const int l = t & 63, w = t >> 6;
  const int wr = w >> 1, wc = w & 1;
  const int m0 = blockIdx.y * 128, n0 = blockIdx.x * 128;
  f32x4 acc[4][4] = {};

  for (int kt = 0; kt < DD; kt += 64) {
    __syncthreads();
    #pragma unroll
    for (int i = 0; i < 2; ++i) {
      const int row = (i * 4 + w) * 16 + (l >> 2);
      const int cc = (l & 3) * 8;
      gload16(xb  + (size_t)(m0 + row) * DD + kt + cc,      &As0[(i * 4 + w) * 512]);
      gload16(xb  + (size_t)(m0 + row) * DD + kt + 32 + cc, &As1[(i * 4 + w) * 512]);
      gload16(Wwb + (size_t)(n0 + row) * DD + kt + cc,      &Bs0[(i * 4 + w) * 512]);
      gload16(Wwb + (size_t)(n0 + row) * DD + kt + 32 + cc, &Bs1[(i * 4 + w) * 512]);
    }
    __syncthreads();
    #pragma unroll
    for (int ks = 0; ks < 2; ++ks) {
      const unsigned short* As = ks ? As1 : As0;
      const unsigned short* Bs = ks ? Bs1 : Bs0;
      bf16x8 a[4], b[4];
      #pragma unroll
      for (int i = 0; i < 4; ++i) {
        a[i] = __builtin_bit_cast(bf16x8, *(const uint4*)&As[(wr * 64 + i * 16 + (l & 15)) * 32 + (l >> 4) * 8]);
        b[i] = __builtin_bit_cast(bf16x8, *(const uint4*)&Bs[(wc * 64 + i * 16 + (l & 15)) * 32 + (l >> 4) * 8]);
      }
      #pragma unroll
      for (int i = 0; i < 4; ++i)
        #pragma unroll
        for (int j = 0; j < 4; ++j)
          acc[i][j] = __builtin_amdgcn_mfma_f32_16x16x32_bf16(a[i], b[j], acc[i][j], 0, 0, 0);
    }
  }
  __syncthreads();

  // epilogue: acc -> LDS transpose tile (pitch 136 for aligned uint4 reads)
  unsigned short* Tt = Sh;   // reuse (post-barrier)
  const bool isq = (n0 < 1024);
  const bool isv = (n0 >= 2048);
  #pragma unroll
  for (int i = 0; i < 4; ++i)
    #pragma unroll
    for (int j = 0; j < 4; ++j)
      #pragma unroll
      for (int r = 0; r < 4; ++r) {
        const int rr = wr * 64 + i * 16 + (l >> 4) * 4 + r;
        const int cl = wc * 64 + j * 16 + (l & 15);
        float v = acc[i][j][r] + Wb[n0 + cl];
        if (isq) v *= 0.04508422f;               // (1/32)*log2(e)
        Tt[rr * 136 + cl] = f2bf_fast(v);
      }
  __syncthreads();
  const int bidx = m0 >> 11, srow0 = m0 & 2047;

  if (!isv) {
    // q/k tile: coalesced uint4 stores into [b,h,s,hd]
    unsigned short* dstb = isq ? qb : kb;
    const int nh0 = (n0 & 1023) >> 6;            // first head in this tile
    const int q4 = t & 3;
    #pragma unroll
    for (int ci = 0; ci < 4; ++ci) {
      const int combo = ci * 64 + (t >> 2);      // 0..255 = 128 rows x 2 halves
      const int row = combo >> 1, hh = combo & 1;
      const int head = nh0 + hh;
      unsigned short* dst = dstb + ((size_t)(bidx * HH + head) * SS + srow0 + row) * HDIM + q4 * 16;
      *(uint4*)dst       = *(const uint4*)&Tt[row * 136 + hh * 64 + q4 * 16];
      *(uint4*)(dst + 8) = *(const uint4*)&Tt[row * 136 + hh * 64 + q4 * 16 + 8];
    }
  } else {
    // V tile: transpose reads, coalesced stores into vbT[b,h,hd,s]
    const int q = t & 3;
    #pragma unroll
    for (int ci = 0; ci < 2; ++ci) {
      const int c = ci * 64 + (t >> 2);
      const int vcol = n0 - 2048 + c;
      const int head = vcol >> 6, hd = vcol & 63;
      unsigned short* dst = vbT + ((size_t)(bidx * HH + head) * HDIM + hd) * SS + srow0;
      #pragma unroll
      for (int e8 = 0; e8 < 4; ++e8) {
        const int r0 = e8 * 32 + q * 8;
        union { unsigned short us[8]; uint4 v; } pk;
        #pragma unroll
        for (int e = 0; e < 8; ++e) pk.us[e] = Tt[(r0 + e) * 136 + c];
        *(uint4*)(dst + r0) = pk.v;   // 4 lanes (q) x 16B = 64B contiguous per c
      }
    }
  }
}

// ---------------------------------------------------------------------------
// Attention: k-split across waves, barrier-free loops.
// pass-1 row sums now use 32x32x16 MFMA (sum is layout-agnostic: every
// (k,q) score appears exactly once across the lane pair l/l^32 per q-col).
// pass-2 unchanged: 16x16 swapped QK^T -> D[k][q], dense K=32 PV.
// ---------------------------------------------------------------------------
__global__ __launch_bounds__(256) void attn_kernel(
    const unsigned short* __restrict__ qb,
    const unsigned short* __restrict__ kb,
    const unsigned short* __restrict__ vbT,
    unsigned short* __restrict__ ob,
    float* __restrict__ attn_out) {
  __shared__ float Ored[4][64][68];   // [wave][q][d] padded
  __shared__ float Lred[4][64];
  const int t = threadIdx.x;
  const int l = t & 63, w = t >> 6;
  const int q_l = l & 15, hi = l >> 4;
  const int bid = blockIdx.x;
  const int swz = (bid & 7) * 128 + (bid >> 3);
  const int bh = swz >> 5;
  const int q0 = (swz & 31) * 64;
  const size_t base = (size_t)bh * SS * HDIM;

  // ---------------- pass 1: row sums via 32x32x16 MFMA ----------------
  {
    const int l32 = l & 31, h2 = l >> 5;
    // Q B-frags: qB[qb2][d4] = Q[q0 + qb2*32 + l32][d4*16 + h2*8 .. +7]
    bf16x8 qB[2][4];
    #pragma unroll
    for (int qb2 = 0; qb2 < 2; ++qb2)
      #pragma unroll
      for (int d4 = 0; d4 < 4; ++d4)
        qB[qb2][d4] = __builtin_bit_cast(bf16x8,
            *(const uint4*)(qb + base + (size_t)(q0 + qb2 * 32 + l32) * HDIM + d4 * 16 + h2 * 8));
    // K A-frag base: row = kt + w*32 + l32, cols d4*16 + h2*8
    const unsigned short* kga32 = kb + base + (size_t)(w * 32 + l32) * HDIM + h2 * 8;

    float ls2[2] = {0.f, 0.f};
    for (int kt = 0; kt < SS; kt += 128) {
      bf16x8 kA[4];
      #pragma unroll
      for (int d4 = 0; d4 < 4; ++d4)
        kA[d4] = __builtin_bit_cast(bf16x8, *(const uint4*)(kga32 + (size_t)kt * HDIM + d4 * 16));
      #pragma unroll
      for (int qb2 = 0; qb2 < 2; ++qb2) {
        f32x16 acc = {};
        __builtin_amdgcn_s_setprio(1);
        #pragma unroll
        for (int d4 = 0; d4 < 4; ++d4)
          acc = __builtin_amdgcn_mfma_f32_32x32x16_bf16(kA[d4], qB[qb2][d4], acc, 0, 0, 0);
        __builtin_amdgcn_s_setprio(0);
        #pragma unroll
        for (int r = 0; r < 16; ++r)
          ls2[qb2] += __builtin_amdgcn_exp2f(acc[r]);
      }
    }
    #pragma unroll
    for (int qb2 = 0; qb2 < 2; ++qb2)
      ls2[qb2] += __shfl_xor(ls2[qb2], 32);
    if (l < 32) {
      Lred[w][l]      = ls2[0];
      Lred[w][32 + l] = ls2[1];
    }
  }
  __syncthreads();
  float rl[4];
  #pragma unroll
  for (int j = 0; j < 4; ++j)
    rl[j] = 1.0f / (Lred[0][j * 16 + q_l] + Lred[1][j * 16 + q_l] +
                    Lred[2][j * 16 + q_l] + Lred[3][j * 16 + q_l]);

  // Q B-fragments for pass-2 (16x16 layout)
  bf16x8 qa[4][2];
  #pragma unroll
  for (int j = 0; j < 4; ++j)
    #pragma unroll
    for (int kc = 0; kc < 2; ++kc)
      qa[j][kc] = __builtin_bit_cast(bf16x8,
          *(const uint4*)(qb + base + (size_t)(q0 + j * 16 + q_l) * HDIM + kc * 32 + hi * 8));

  const unsigned short* kga = kb + base + (size_t)(w * 16 + q_l) * HDIM + hi * 8;
  const unsigned short* vga = vbT + ((size_t)bh * HDIM + q_l) * SS + w * 16 + hi * 4;

  float* pbs[4];
  #pragma unroll
  for (int j = 0; j < 4; ++j)
    pbs[j] = attn_out + ((size_t)bh * SS + (q0 + j * 16 + q_l)) * SS + w * 16 + hi * 4;

  // ---------------- pass 2: P + O, 128-k tiles, dense K=32 PV -------------
  f32x4 of[4][4] = {};
  for (int kt = 0; kt < SS; kt += 128) {
    const uint4 k0 = *(const uint4*)(kga + (size_t)kt * HDIM);
    const uint4 k1 = *(const uint4*)(kga + (size_t)kt * HDIM + 32);
    const uint4 k2 = *(const uint4*)(kga + (size_t)(kt + 64) * HDIM);
    const uint4 k3 = *(const uint4*)(kga + (size_t)(kt + 64) * HDIM + 32);
    uint2 vv0[4], vv1[4];
    #pragma unroll
    for (int d4 = 0; d4 < 4; ++d4) {
      vv0[d4] = *(const uint2*)(vga + (size_t)(d4 * 16) * SS + kt);
      vv1[d4] = *(const uint2*)(vga + (size_t)(d4 * 16) * SS + kt + 64);
    }
    const bf16x8 kf0 = __builtin_bit_cast(bf16x8, k0);
    const bf16x8 kf1 = __builtin_bit_cast(bf16x8, k1);
    const bf16x8 kf2 = __builtin_bit_cast(bf16x8, k2);
    const bf16x8 kf3 = __builtin_bit_cast(bf16x8, k3);
    f32x4 sQa[4] = {}, sQb[4] = {};
    __builtin_amdgcn_s_setprio(1);
    #pragma unroll
    for (int j = 0; j < 4; ++j) {
      sQa[j] = __builtin_amdgcn_mfma_f32_16x16x32_bf16(kf0, qa[j][0], sQa[j], 0, 0, 0);
      sQa[j] = __builtin_amdgcn_mfma_f32_16x16x32_bf16(kf1, qa[j][1], sQa[j], 0, 0, 0);
      sQb[j] = __builtin_amdgcn_mfma_f32_16x16x32_bf16(kf2, qa[j][0], sQb[j], 0, 0, 0);
      sQb[j] = __builtin_amdgcn_mfma_f32_16x16x32_bf16(kf3, qa[j][1], sQb[j], 0, 0, 0);
    }
    __builtin_amdgcn_s_setprio(0);
    bf16x8 pbp[4];
    #pragma unroll
    for (int j = 0; j < 4; ++j) {
      float4 pva, pvb;
      pva.x = __builtin_amdgcn_exp2f(sQa[j][0]) * rl[j];
      pva.y = __builtin_amdgcn_exp2f(sQa[j][1]) * rl[j];
      pva.z = __builtin_amdgcn_exp2f(sQa[j][2]) * rl[j];
      pva.w = __builtin_amdgcn_exp2f(sQa[j][3]) * rl[j];
      pvb.x = __builtin_amdgcn_exp2f(sQb[j][0]) * rl[j];
      pvb.y = __builtin_amdgcn_exp2f(sQb[j][1]) * rl[j];
      pvb.z = __builtin_amdgcn_exp2f(sQb[j][2]) * rl[j];
      pvb.w = __builtin_amdgcn_exp2f(sQb[j][3]) * rl[j];
      __builtin_nontemporal_store(*(const f32x4*)&pva, (f32x4*)(pbs[j] + kt));
      __builtin_nontemporal_store(*(const f32x4*)&pvb, (f32x4*)(pbs[j] + kt + 64));
      pbp[j] = __builtin_bit_cast(bf16x8, pack8f(pva, pvb));
    }
    __builtin_amdgcn_s_setprio(1);
    #pragma unroll
    for (int d4 = 0; d4 < 4; ++d4) {
      uint4 vp; vp.x = vv0[d4].x; vp.y = vv0[d4].y; vp.z = vv1[d4].x; vp.w = vv1[d4].y;
      const bf16x8 vfp = __builtin_bit_cast(bf16x8, vp);
      #pragma unroll
      for (int j = 0; j < 4; ++j)
        of[d4][j] = __builtin_amdgcn_mfma_f32_16x16x32_bf16(vfp, pbp[j], of[d4][j], 0, 0, 0);
    }
    __builtin_amdgcn_s_setprio(0);
  }

  // ---------------- cross-wave O reduce ----------------
  #pragma unroll
  for (int d4 = 0; d4 < 4; ++d4)
    #pragma unroll
    for (int j = 0; j < 4; ++j)
      *(f32x4*)&Ored[w][j * 16 + q_l][d4 * 16 + hi * 4] = of[d4][j];
  __syncthreads();
  const int bidx = bh >> 4, h_ = bh & 15;
  const int qf = w * 16 + q_l;
  union { unsigned short us[16]; uint4 v[2]; } opk;
  #pragma unroll
  for (int c4 = 0; c4 < 4; ++c4) {
    const int d0 = hi * 16 + c4 * 4;
    f32x4 s = *(const f32x4*)&Ored[0][qf][d0];
    s += *(const f32x4*)&Ored[1][qf][d0];
    s += *(const f32x4*)&Ored[2][qf][d0];
    s += *(const f32x4*)&Ored[3][qf][d0];
    opk.us[c4 * 4 + 0] = f2bf_fast(s[0]);
    opk.us[c4 * 4 + 1] = f2bf_fast(s[1]);
    opk.us[c4 * 4 + 2] = f2bf_fast(s[2]);
    opk.us[c4 * 4 + 3] = f2bf_fast(s[3]);
  }
  unsigned short* orow = ob + ((size_t)bidx * SS + (q0 + qf)) * DD + h_ * 64 + hi * 16;
  *(uint4*)orow = opk.v[0];
  *(uint4*)(orow + 8) = opk.v[1];
}

// ---------------------------------------------------------------------------
// Proj GEMM, BK=64 half-buffers: y = ob @ pwb^T + pb + x (fp32 -> d_out)
// BM=64, BN=128 -> 512 blocks = 2 blocks/CU. (r14 exact)
// ---------------------------------------------------------------------------
__global__ __launch_bounds__(256) void gemm_proj(
    const unsigned short* __restrict__ ob, const unsigned short* __restrict__ pwb,
    const float* __restrict__ pb, const float* __restrict__ x,
    float* __restrict__ y) {
  __shared__ __align__(16) unsigned short Ps[12288];   // 24 KB
  unsigned short* As0 = Ps;            // 64x32
  unsigned short* As1 = Ps + 2048;     // 64x32
  unsigned short* Bs0 = Ps + 4096;     // 128x32
  unsigned short* Bs1 = Ps + 8192;     // 128x32
  const int t = threadIdx.x;
  const int l = t & 63, w = t >> 6;
  const int wr = w >> 1, wc = w & 1;
  const int m0 = blockIdx.y * 64, n0 = blockIdx.x * 128;
  f32x4 acc[2][4] = {};

  for (int kt = 0; kt < DD; kt += 64) {
    __syncthreads();
    {
      const int rowA = w * 16 + (l >> 2);
      const int cc = (l & 3) * 8;
      gload16(ob + (size_t)(m0 + rowA) * DD + kt + cc,      &As0[w * 512]);
      gload16(ob + (size_t)(m0 + rowA) * DD + kt + 32 + cc, &As1[w * 512]);
      #pragma unroll
      for (int i = 0; i < 2; ++i) {
        const int rowB = (i * 4 + w) * 16 + (l >> 2);
        gload16(pwb + (size_t)(n0 + rowB) * DD + kt + cc,      &Bs0[(i * 4 + w) * 512]);
        gload16(pwb + (size_t)(n0 + rowB) * DD + kt + 32 + cc, &Bs1[(i * 4 + w) * 512]);
      }
    }
    __syncthreads();
    #pragma unroll
    for (int ks = 0; ks < 2; ++ks) {
      const unsigned short* As = ks ? As1 : As0;
      const unsigned short* Bs = ks ? Bs1 : Bs0;
      bf16x8 a[2], b[4];
      #pragma unroll
      for (int i = 0; i < 2; ++i)
        a[i] = __builtin_bit_cast(bf16x8, *(const uint4*)&As[(wr * 32 + i * 16 + (l & 15)) * 32 + (l >> 4) * 8]);
      #pragma unroll
      for (int j = 0; j < 4; ++j)
        b[j] = __builtin_bit_cast(bf16x8, *(const uint4*)&Bs[(wc * 64 + j * 16 + (l & 15)) * 32 + (l >> 4) * 8]);
      #pragma unroll
      for (int i = 0; i < 2; ++i)
        #pragma unroll
        for (int j = 0; j < 4; ++j)
          acc[i][j] = __builtin_amdgcn_mfma_f32_16x16x32_bf16(a[i], b[j], acc[i][j], 0, 0, 0);
    }
  }
  #pragma unroll
  for (int i = 0; i < 2; ++i)
    #pragma unroll
    for (int j = 0; j < 4; ++j)
      #pragma unroll
      for (int r = 0; r < 4; ++r) {
        const int row = m0 + wr * 32 + i * 16 + (l >> 4) * 4 + r;
        const int col = n0 + wc * 64 + j * 16 + (l & 15);
        const size_t idx = (size_t)row * DD + col;
        y[idx] = acc[i][j][r] + pb[col] + x[idx];
      }
}

// ---------------------------------------------------------------------------
// LayerNorm over d=1024 per row, IN PLACE on d_out
// ---------------------------------------------------------------------------
__global__ __launch_bounds__(256) void ln_kernel(
    float* __restrict__ y, const float* __restrict__ gamma,
    const float* __restrict__ beta) {
  const int row = blockIdx.x;
  const int t = threadIdx.x;
  const float4 v = ((const float4*)(y + (size_t)row * DD))[t];
  float s  = v.x + v.y + v.z + v.w;
  float s2 = v.x * v.x + v.y * v.y + v.z * v.z + v.w * v.w;
  #pragma unroll
  for (int off = 1; off < 64; off <<= 1) { s += __shfl_xor(s, off); s2 += __shfl_xor(s2, off); }
  __shared__ float red[8];
  const int l = t & 63, w = t >> 6;
  if (l == 0) { red[w] = s; red[4 + w] = s2; }
  __syncthreads();
  s  = red[0] + red[1] + red[2] + red[3];
  s2 = red[4] + red[5] + red[6] + red[7];
  const float mu = s * (1.0f / DD);
  const float var = s2 * (1.0f / DD) - mu * mu;
  const float rs = rsqrtf(var + 1e-5f);
  const float4 g  = ((const float4*)gamma)[t];
  const float4 be = ((const float4*)beta)[t];
  float4 o;
  o.x = (v.x - mu) * rs * g.x + be.x;
  o.y = (v.y - mu) * rs * g.y + be.y;
  o.z = (v.z - mu) * rs * g.z + be.z;
  o.w = (v.w - mu) * rs * g.w + be.w;
  ((float4*)(y + (size_t)row * DD))[t] = o;
}

extern "C" void kernel_launch(void* const* d_in, const int* in_sizes, int n_in,
                              void* d_out, int out_size, void* d_ws, size_t ws_size,
                              hipStream_t stream) {
  const float* x     = (const float*)d_in[0];
  const float* Ww    = (const float*)d_in[1];
  const float* Wb    = (const float*)d_in[2];
  const float* Pw    = (const float*)d_in[3];
  const float* Pb    = (const float*)d_in[4];
  const float* gamma = (const float*)d_in[5];
  const float* beta  = (const float*)d_in[6];

  float* out      = (float*)d_out;
  float* y_norm   = out;                       // 4,194,304 floats
  float* attn_out = out + (size_t)MM * DD;     // 134,217,728 floats

  char* ws = (char*)d_ws;                      // 48 MiB
  unsigned short* qb  = (unsigned short*)(ws);
  unsigned short* kb  = (unsigned short*)(ws +  8388608);
  unsigned short* vbT = (unsigned short*)(ws + 16777216);
  unsigned short* ob  = (unsigned short*)(ws + 25165824);
  unsigned short* xb  = (unsigned short*)(ws + 33554432);
  unsigned short* Wwb = (unsigned short*)(ws + 41943040);
  unsigned short* pwb = (unsigned short*)(ws + 48234496);

  cvt_kernel<<<4096, 256, 0, stream>>>(x, Ww, Pw, xb, Wwb, pwb);
  gemm_qkv<<<dim3(N3 / 128, MM / 128), 256, 0, stream>>>(xb, Wwb, Wb, qb, kb, vbT);
  attn_kernel<<<1024, 256, 0, stream>>>(qb, kb, vbT, ob, attn_out);
  gemm_proj<<<dim3(DD / 128, MM / 64), 256, 0, stream>>>(ob, pwb, Pb, x, y_norm);
  ln_kernel<<<MM, 256, 0, stream>>>(y_norm, gamma, beta);
}

// Round 19
// 232.260 us; speedup vs baseline: 1.0239x; 1.0239x over previous
//
#include <hip/hip_runtime.h>
#include <cstdint>

#define BB 2
#define SS 2048
#define DD 1024
#define HH 16
#define HDIM 64
#define MM (BB*SS)      // 4096
#define N3 (3*DD)       // 3072

typedef __attribute__((ext_vector_type(4))) float f32x4;
typedef __attribute__((ext_vector_type(8))) __bf16 bf16x8;

static __device__ __forceinline__ unsigned short f2bf_fast(float f) {
  __bf16 h = (__bf16)f;
  return __builtin_bit_cast(unsigned short, h);
}

static __device__ __forceinline__ uint4 pack8f(const float4 a, const float4 b) {
  union { unsigned short us[8]; uint4 v; } pk;
  pk.us[0] = f2bf_fast(a.x); pk.us[1] = f2bf_fast(a.y); pk.us[2] = f2bf_fast(a.z); pk.us[3] = f2bf_fast(a.w);
  pk.us[4] = f2bf_fast(b.x); pk.us[5] = f2bf_fast(b.y); pk.us[6] = f2bf_fast(b.z); pk.us[7] = f2bf_fast(b.w);
  return pk.v;
}

static __device__ __forceinline__ void gload16(const unsigned short* g, unsigned short* l) {
  __builtin_amdgcn_global_load_lds(
      (const __attribute__((address_space(1))) void*)g,
      (__attribute__((address_space(3))) void*)l, 16, 0, 0);
}

// ---------------------------------------------------------------------------
// One-time fp32 -> bf16 conversion of x, W_w, proj_w
// ---------------------------------------------------------------------------
__global__ __launch_bounds__(256) void cvt_kernel(
    const float* __restrict__ x, const float* __restrict__ Ww,
    const float* __restrict__ pw,
    unsigned short* __restrict__ xb, unsigned short* __restrict__ Wwb,
    unsigned short* __restrict__ pwb) {
  const size_t i = ((size_t)blockIdx.x * 256 + threadIdx.x) * 8;
  const float* src;
  unsigned short* dst;
  if (i < 4194304u)       { src = x  + i;            dst = xb  + i; }
  else if (i < 7340032u)  { src = Ww + (i - 4194304u); dst = Wwb + (i - 4194304u); }
  else                    { src = pw + (i - 7340032u); dst = pwb + (i - 7340032u); }
  const float4* s4 = (const float4*)src;
  *(uint4*)dst = pack8f(s4[0], s4[1]);
}

// ---------------------------------------------------------------------------
// QKV GEMM (bf16 in), BK=64 via two 128x32 half-buffers per operand.
// ALL outputs (q, k, v) go through an LDS transpose tile -> coalesced
// uint4 stores. q pre-scaled by log2e/32; v transposed to [b,h,hd,s].
// (r17 exact)
// ---------------------------------------------------------------------------
__global__ __launch_bounds__(256) void gemm_qkv(
    const unsigned short* __restrict__ xb, const unsigned short* __restrict__ Wwb,
    const float* __restrict__ Wb,
    unsigned short* __restrict__ qb, unsigned short* __restrict__ kb,
    unsigned short* __restrict__ vbT) {
  __shared__ __align__(16) unsigned short Sh[128 * 136];   // 34.8 KB
  unsigned short* As0 = Sh;                 // 128x32 (k lo)
  unsigned short* As1 = Sh + 4096;          // 128x32 (k hi)
  unsigned short* Bs0 = Sh + 8192;
  unsigned short* Bs1 = Sh + 12288;
  const int t = threadIdx.x;
  const int l = t & 63, w = t >> 6;
  const int wr = w >> 1, wc = w & 1;
  const int m0 = blockIdx.y * 128, n0 = blockIdx.x * 128;
  f32x4 acc[4][4] = {};

  for (int kt = 0; kt < DD; kt += 64) {
    __syncthreads();
    #pragma unroll
    for (int i = 0; i < 2; ++i) {
      const int row = (i * 4 + w) * 16 + (l >> 2);
      const int cc = (l & 3) * 8;
      gload16(xb  + (size_t)(m0 + row) * DD + kt + cc,      &As0[(i * 4 + w) * 512]);
      gload16(xb  + (size_t)(m0 + row) * DD + kt + 32 + cc, &As1[(i * 4 + w) * 512]);
      gload16(Wwb + (size_t)(n0 + row) * DD + kt + cc,      &Bs0[(i * 4 + w) * 512]);
      gload16(Wwb + (size_t)(n0 + row) * DD + kt + 32 + cc, &Bs1[(i * 4 + w) * 512]);
    }
    __syncthreads();
    #pragma unroll
    for (int ks = 0; ks < 2; ++ks) {
      const unsigned short* As = ks ? As1 : As0;
      const unsigned short* Bs = ks ? Bs1 : Bs0;
      bf16x8 a[4], b[4];
      #pragma unroll
      for (int i = 0; i < 4; ++i) {
        a[i] = __builtin_bit_cast(bf16x8, *(const uint4*)&As[(wr * 64 + i * 16 + (l & 15)) * 32 + (l >> 4) * 8]);
        b[i] = __builtin_bit_cast(bf16x8, *(const uint4*)&Bs[(wc * 64 + i * 16 + (l & 15)) * 32 + (l >> 4) * 8]);
      }
      #pragma unroll
      for (int i = 0; i < 4; ++i)
        #pragma unroll
        for (int j = 0; j < 4; ++j)
          acc[i][j] = __builtin_amdgcn_mfma_f32_16x16x32_bf16(a[i], b[j], acc[i][j], 0, 0, 0);
    }
  }
  __syncthreads();

  // epilogue: acc -> LDS transpose tile (pitch 136 for aligned uint4 reads)
  unsigned short* Tt = Sh;   // reuse (post-barrier)
  const bool isq = (n0 < 1024);
  const bool isv = (n0 >= 2048);
  #pragma unroll
  for (int i = 0; i < 4; ++i)
    #pragma unroll
    for (int j = 0; j < 4; ++j)
      #pragma unroll
      for (int r = 0; r < 4; ++r) {
        const int rr = wr * 64 + i * 16 + (l >> 4) * 4 + r;
        const int cl = wc * 64 + j * 16 + (l & 15);
        float v = acc[i][j][r] + Wb[n0 + cl];
        if (isq) v *= 0.04508422f;               // (1/32)*log2(e)
        Tt[rr * 136 + cl] = f2bf_fast(v);
      }
  __syncthreads();
  const int bidx = m0 >> 11, srow0 = m0 & 2047;

  if (!isv) {
    // q/k tile: coalesced uint4 stores into [b,h,s,hd]
    unsigned short* dstb = isq ? qb : kb;
    const int nh0 = (n0 & 1023) >> 6;            // first head in this tile
    const int q4 = t & 3;
    #pragma unroll
    for (int ci = 0; ci < 4; ++ci) {
      const int combo = ci * 64 + (t >> 2);      // 0..255 = 128 rows x 2 halves
      const int row = combo >> 1, hh = combo & 1;
      const int head = nh0 + hh;
      unsigned short* dst = dstb + ((size_t)(bidx * HH + head) * SS + srow0 + row) * HDIM + q4 * 16;
      *(uint4*)dst       = *(const uint4*)&Tt[row * 136 + hh * 64 + q4 * 16];
      *(uint4*)(dst + 8) = *(const uint4*)&Tt[row * 136 + hh * 64 + q4 * 16 + 8];
    }
  } else {
    // V tile: transpose reads, coalesced stores into vbT[b,h,hd,s]
    const int q = t & 3;
    #pragma unroll
    for (int ci = 0; ci < 2; ++ci) {
      const int c = ci * 64 + (t >> 2);
      const int vcol = n0 - 2048 + c;
      const int head = vcol >> 6, hd = vcol & 63;
      unsigned short* dst = vbT + ((size_t)(bidx * HH + head) * HDIM + hd) * SS + srow0;
      #pragma unroll
      for (int e8 = 0; e8 < 4; ++e8) {
        const int r0 = e8 * 32 + q * 8;
        union { unsigned short us[8]; uint4 v; } pk;
        #pragma unroll
        for (int e = 0; e < 8; ++e) pk.us[e] = Tt[(r0 + e) * 136 + c];
        *(uint4*)(dst + r0) = pk.v;   // 4 lanes (q) x 16B = 64B contiguous per c
      }
    }
  }
}

// ---------------------------------------------------------------------------
// Attention (r13/r14 best, verbatim): k-split across waves, barrier-free
// loops, swapped QK^T -> D[k][q], pass-2 packs two 16-k slices into
// fully-dense K=32 PV MFMA.
// ---------------------------------------------------------------------------
__global__ __launch_bounds__(256) void attn_kernel(
    const unsigned short* __restrict__ qb,
    const unsigned short* __restrict__ kb,
    const unsigned short* __restrict__ vbT,
    unsigned short* __restrict__ ob,
    float* __restrict__ attn_out) {
  __shared__ float Ored[4][64][68];   // [wave][q][d] padded
  __shared__ float Lred[4][64];
  const int t = threadIdx.x;
  const int l = t & 63, w = t >> 6;
  const int q_l = l & 15, hi = l >> 4;
  const int bid = blockIdx.x;
  const int swz = (bid & 7) * 128 + (bid >> 3);
  const int bh = swz >> 5;
  const int q0 = (swz & 31) * 64;
  const size_t base = (size_t)bh * SS * HDIM;

  bf16x8 qa[4][2];
  #pragma unroll
  for (int j = 0; j < 4; ++j)
    #pragma unroll
    for (int kc = 0; kc < 2; ++kc)
      qa[j][kc] = __builtin_bit_cast(bf16x8,
          *(const uint4*)(qb + base + (size_t)(q0 + j * 16 + q_l) * HDIM + kc * 32 + hi * 8));

  const unsigned short* kga = kb + base + (size_t)(w * 16 + q_l) * HDIM + hi * 8;
  const unsigned short* vga = vbT + ((size_t)bh * HDIM + q_l) * SS + w * 16 + hi * 4;

  // ---------------- pass 1: row sums (no barriers) ----------------
  float lsum[4] = {0.f, 0.f, 0.f, 0.f};
  {
    uint4 k0 = *(const uint4*)(kga);
    uint4 k1 = *(const uint4*)(kga + 32);
    for (int kt = 0; kt < SS; kt += 64) {
      const bool more = (kt + 64) < SS;
      uint4 n0, n1;
      if (more) {
        n0 = *(const uint4*)(kga + (size_t)(kt + 64) * HDIM);
        n1 = *(const uint4*)(kga + (size_t)(kt + 64) * HDIM + 32);
      }
      f32x4 sQ[4] = {};
      const bf16x8 kf0 = __builtin_bit_cast(bf16x8, k0);
      const bf16x8 kf1 = __builtin_bit_cast(bf16x8, k1);
      __builtin_amdgcn_s_setprio(1);
      #pragma unroll
      for (int j = 0; j < 4; ++j) {
        sQ[j] = __builtin_amdgcn_mfma_f32_16x16x32_bf16(kf0, qa[j][0], sQ[j], 0, 0, 0);
        sQ[j] = __builtin_amdgcn_mfma_f32_16x16x32_bf16(kf1, qa[j][1], sQ[j], 0, 0, 0);
      }
      __builtin_amdgcn_s_setprio(0);
      #pragma unroll
      for (int j = 0; j < 4; ++j)
        #pragma unroll
        for (int r = 0; r < 4; ++r)
          lsum[j] += __builtin_amdgcn_exp2f(sQ[j][r]);
      k0 = n0; k1 = n1;
    }
  }
  #pragma unroll
  for (int j = 0; j < 4; ++j) {
    float s = lsum[j];
    s += __shfl_xor(s, 16);
    s += __shfl_xor(s, 32);
    lsum[j] = s;
  }
  if (hi == 0) {
    #pragma unroll
    for (int j = 0; j < 4; ++j) Lred[w][j * 16 + q_l] = lsum[j];
  }
  __syncthreads();
  float rl[4];
  #pragma unroll
  for (int j = 0; j < 4; ++j)
    rl[j] = 1.0f / (Lred[0][j * 16 + q_l] + Lred[1][j * 16 + q_l] +
                    Lred[2][j * 16 + q_l] + Lred[3][j * 16 + q_l]);

  float* pbs[4];
  #pragma unroll
  for (int j = 0; j < 4; ++j)
    pbs[j] = attn_out + ((size_t)bh * SS + (q0 + j * 16 + q_l)) * SS + w * 16 + hi * 4;

  // ---------------- pass 2: P + O, 128-k tiles, dense K=32 PV -------------
  f32x4 of[4][4] = {};
  for (int kt = 0; kt < SS; kt += 128) {
    const uint4 k0 = *(const uint4*)(kga + (size_t)kt * HDIM);
    const uint4 k1 = *(const uint4*)(kga + (size_t)kt * HDIM + 32);
    const uint4 k2 = *(const uint4*)(kga + (size_t)(kt + 64) * HDIM);
    const uint4 k3 = *(const uint4*)(kga + (size_t)(kt + 64) * HDIM + 32);
    uint2 vv0[4], vv1[4];
    #pragma unroll
    for (int d4 = 0; d4 < 4; ++d4) {
      vv0[d4] = *(const uint2*)(vga + (size_t)(d4 * 16) * SS + kt);
      vv1[d4] = *(const uint2*)(vga + (size_t)(d4 * 16) * SS + kt + 64);
    }
    const bf16x8 kf0 = __builtin_bit_cast(bf16x8, k0);
    const bf16x8 kf1 = __builtin_bit_cast(bf16x8, k1);
    const bf16x8 kf2 = __builtin_bit_cast(bf16x8, k2);
    const bf16x8 kf3 = __builtin_bit_cast(bf16x8, k3);
    f32x4 sQa[4] = {}, sQb[4] = {};
    __builtin_amdgcn_s_setprio(1);
    #pragma unroll
    for (int j = 0; j < 4; ++j) {
      sQa[j] = __builtin_amdgcn_mfma_f32_16x16x32_bf16(kf0, qa[j][0], sQa[j], 0, 0, 0);
      sQa[j] = __builtin_amdgcn_mfma_f32_16x16x32_bf16(kf1, qa[j][1], sQa[j], 0, 0, 0);
      sQb[j] = __builtin_amdgcn_mfma_f32_16x16x32_bf16(kf2, qa[j][0], sQb[j], 0, 0, 0);
      sQb[j] = __builtin_amdgcn_mfma_f32_16x16x32_bf16(kf3, qa[j][1], sQb[j], 0, 0, 0);
    }
    __builtin_amdgcn_s_setprio(0);
    bf16x8 pbp[4];
    #pragma unroll
    for (int j = 0; j < 4; ++j) {
      float4 pva, pvb;
      pva.x = __builtin_amdgcn_exp2f(sQa[j][0]) * rl[j];
      pva.y = __builtin_amdgcn_exp2f(sQa[j][1]) * rl[j];
      pva.z = __builtin_amdgcn_exp2f(sQa[j][2]) * rl[j];
      pva.w = __builtin_amdgcn_exp2f(sQa[j][3]) * rl[j];
      pvb.x = __builtin_amdgcn_exp2f(sQb[j][0]) * rl[j];
      pvb.y = __builtin_amdgcn_exp2f(sQb[j][1]) * rl[j];
      pvb.z = __builtin_amdgcn_exp2f(sQb[j][2]) * rl[j];
      pvb.w = __builtin_amdgcn_exp2f(sQb[j][3]) * rl[j];
      __builtin_nontemporal_store(*(const f32x4*)&pva, (f32x4*)(pbs[j] + kt));
      __builtin_nontemporal_store(*(const f32x4*)&pvb, (f32x4*)(pbs[j] + kt + 64));
      pbp[j] = __builtin_bit_cast(bf16x8, pack8f(pva, pvb));
    }
    __builtin_amdgcn_s_setprio(1);
    #pragma unroll
    for (int d4 = 0; d4 < 4; ++d4) {
      uint4 vp; vp.x = vv0[d4].x; vp.y = vv0[d4].y; vp.z = vv1[d4].x; vp.w = vv1[d4].y;
      const bf16x8 vfp = __builtin_bit_cast(bf16x8, vp);
      #pragma unroll
      for (int j = 0; j < 4; ++j)
        of[d4][j] = __builtin_amdgcn_mfma_f32_16x16x32_bf16(vfp, pbp[j], of[d4][j], 0, 0, 0);
    }
    __builtin_amdgcn_s_setprio(0);
  }

  // ---------------- cross-wave O reduce ----------------
  #pragma unroll
  for (int d4 = 0; d4 < 4; ++d4)
    #pragma unroll
    for (int j = 0; j < 4; ++j)
      *(f32x4*)&Ored[w][j * 16 + q_l][d4 * 16 + hi * 4] = of[d4][j];
  __syncthreads();
  const int bidx = bh >> 4, h_ = bh & 15;
  const int qf = w * 16 + q_l;
  union { unsigned short us[16]; uint4 v[2]; } opk;
  #pragma unroll
  for (int c4 = 0; c4 < 4; ++c4) {
    const int d0 = hi * 16 + c4 * 4;
    f32x4 s = *(const f32x4*)&Ored[0][qf][d0];
    s += *(const f32x4*)&Ored[1][qf][d0];
    s += *(const f32x4*)&Ored[2][qf][d0];
    s += *(const f32x4*)&Ored[3][qf][d0];
    opk.us[c4 * 4 + 0] = f2bf_fast(s[0]);
    opk.us[c4 * 4 + 1] = f2bf_fast(s[1]);
    opk.us[c4 * 4 + 2] = f2bf_fast(s[2]);
    opk.us[c4 * 4 + 3] = f2bf_fast(s[3]);
  }
  unsigned short* orow = ob + ((size_t)bidx * SS + (q0 + qf)) * DD + h_ * 64 + hi * 16;
  *(uint4*)orow = opk.v[0];
  *(uint4*)(orow + 8) = opk.v[1];
}

// ---------------------------------------------------------------------------
// Proj GEMM, BK=64 half-buffers: y = ob @ pwb^T + pb + x (fp32 -> d_out)
// BM=64, BN=128 -> 512 blocks = 2 blocks/CU. (r14 exact)
// ---------------------------------------------------------------------------
__global__ __launch_bounds__(256) void gemm_proj(
    const unsigned short* __restrict__ ob, const unsigned short* __restrict__ pwb,
    const float* __restrict__ pb, const float* __restrict__ x,
    float* __restrict__ y) {
  __shared__ __align__(16) unsigned short Ps[12288];   // 24 KB
  unsigned short* As0 = Ps;            // 64x32
  unsigned short* As1 = Ps + 2048;     // 64x32
  unsigned short* Bs0 = Ps + 4096;     // 128x32
  unsigned short* Bs1 = Ps + 8192;     // 128x32
  const int t = threadIdx.x;
  const int l = t & 63, w = t >> 6;
  const int wr = w >> 1, wc = w & 1;
  const int m0 = blockIdx.y * 64, n0 = blockIdx.x * 128;
  f32x4 acc[2][4] = {};

  for (int kt = 0; kt < DD; kt += 64) {
    __syncthreads();
    {
      const int rowA = w * 16 + (l >> 2);
      const int cc = (l & 3) * 8;
      gload16(ob + (size_t)(m0 + rowA) * DD + kt + cc,      &As0[w * 512]);
      gload16(ob + (size_t)(m0 + rowA) * DD + kt + 32 + cc, &As1[w * 512]);
      #pragma unroll
      for (int i = 0; i < 2; ++i) {
        const int rowB = (i * 4 + w) * 16 + (l >> 2);
        gload16(pwb + (size_t)(n0 + rowB) * DD + kt + cc,      &Bs0[(i * 4 + w) * 512]);
        gload16(pwb + (size_t)(n0 + rowB) * DD + kt + 32 + cc, &Bs1[(i * 4 + w) * 512]);
      }
    }
    __syncthreads();
    #pragma unroll
    for (int ks = 0; ks < 2; ++ks) {
      const unsigned short* As = ks ? As1 : As0;
      const unsigned short* Bs = ks ? Bs1 : Bs0;
      bf16x8 a[2], b[4];
      #pragma unroll
      for (int i = 0; i < 2; ++i)
        a[i] = __builtin_bit_cast(bf16x8, *(const uint4*)&As[(wr * 32 + i * 16 + (l & 15)) * 32 + (l >> 4) * 8]);
      #pragma unroll
      for (int j = 0; j < 4; ++j)
        b[j] = __builtin_bit_cast(bf16x8, *(const uint4*)&Bs[(wc * 64 + j * 16 + (l & 15)) * 32 + (l >> 4) * 8]);
      #pragma unroll
      for (int i = 0; i < 2; ++i)
        #pragma unroll
        for (int j = 0; j < 4; ++j)
          acc[i][j] = __builtin_amdgcn_mfma_f32_16x16x32_bf16(a[i], b[j], acc[i][j], 0, 0, 0);
    }
  }
  #pragma unroll
  for (int i = 0; i < 2; ++i)
    #pragma unroll
    for (int j = 0; j < 4; ++j)
      #pragma unroll
      for (int r = 0; r < 4; ++r) {
        const int row = m0 + wr * 32 + i * 16 + (l >> 4) * 4 + r;
        const int col = n0 + wc * 64 + j * 16 + (l & 15);
        const size_t idx = (size_t)row * DD + col;
        y[idx] = acc[i][j][r] + pb[col] + x[idx];
      }
}

// ---------------------------------------------------------------------------
// LayerNorm over d=1024 per row, IN PLACE on d_out
// ---------------------------------------------------------------------------
__global__ __launch_bounds__(256) void ln_kernel(
    float* __restrict__ y, const float* __restrict__ gamma,
    const float* __restrict__ beta) {
  const int row = blockIdx.x;
  const int t = threadIdx.x;
  const float4 v = ((const float4*)(y + (size_t)row * DD))[t];
  float s  = v.x + v.y + v.z + v.w;
  float s2 = v.x * v.x + v.y * v.y + v.z * v.z + v.w * v.w;
  #pragma unroll
  for (int off = 1; off < 64; off <<= 1) { s += __shfl_xor(s, off); s2 += __shfl_xor(s2, off); }
  __shared__ float red[8];
  const int l = t & 63, w = t >> 6;
  if (l == 0) { red[w] = s; red[4 + w] = s2; }
  __syncthreads();
  s  = red[0] + red[1] + red[2] + red[3];
  s2 = red[4] + red[5] + red[6] + red[7];
  const float mu = s * (1.0f / DD);
  const float var = s2 * (1.0f / DD) - mu * mu;
  const float rs = rsqrtf(var + 1e-5f);
  const float4 g  = ((const float4*)gamma)[t];
  const float4 be = ((const float4*)beta)[t];
  float4 o;
  o.x = (v.x - mu) * rs * g.x + be.x;
  o.y = (v.y - mu) * rs * g.y + be.y;
  o.z = (v.z - mu) * rs * g.z + be.z;
  o.w = (v.w - mu) * rs * g.w + be.w;
  ((float4*)(y + (size_t)row * DD))[t] = o;
}

extern "C" void kernel_launch(void* const* d_in, const int* in_sizes, int n_in,
                              void* d_out, int out_size, void* d_ws, size_t ws_size,
                              hipStream_t stream) {
  const float* x     = (const float*)d_in[0];
  const float* Ww    = (const float*)d_in[1];
  const float* Wb    = (const float*)d_in[2];
  const float* Pw    = (const float*)d_in[3];
  const float* Pb    = (const float*)d_in[4];
  const float* gamma = (const float*)d_in[5];
  const float* beta  = (const float*)d_in[6];

  float* out      = (float*)d_out;
  float* y_norm   = out;                       // 4,194,304 floats
  float* attn_out = out + (size_t)MM * DD;     // 134,217,728 floats

  char* ws = (char*)d_ws;                      // 48 MiB
  unsigned short* qb  = (unsigned short*)(ws);
  unsigned short* kb  = (unsigned short*)(ws +  8388608);
  unsigned short* vbT = (unsigned short*)(ws + 16777216);
  unsigned short* ob  = (unsigned short*)(ws + 25165824);
  unsigned short* xb  = (unsigned short*)(ws + 33554432);
  unsigned short* Wwb = (unsigned short*)(ws + 41943040);
  unsigned short* pwb = (unsigned short*)(ws + 48234496);

  cvt_kernel<<<4096, 256, 0, stream>>>(x, Ww, Pw, xb, Wwb, pwb);
  gemm_qkv<<<dim3(N3 / 128, MM / 128), 256, 0, stream>>>(xb, Wwb, Wb, qb, kb, vbT);
  attn_kernel<<<1024, 256, 0, stream>>>(qb, kb, vbT, ob, attn_out);
  gemm_proj<<<dim3(DD / 128, MM / 64), 256, 0, stream>>>(ob, pwb, Pb, x, y_norm);
  ln_kernel<<<MM, 256, 0, stream>>>(y_norm, gamma, beta);
}